// Round 1
// baseline (348.065 us; speedup 1.0000x reference)
//
#include <hip/hip_runtime.h>
#include <hip/hip_bf16.h>

// Problem constants (fixed by the reference)
#define DDIM   200
#define CSEG   50000
#define TTOT   1000000
#define BROWS  1024
#define KPAD   224      // 7 * 32 (K padded for mfma 16x16x32)
#define NTILE  64
#define NT     782      // ceil(50000/64)
#define NPAD   50048    // NT*64
#define MTILES 8        // 1024 / 128

typedef __attribute__((ext_vector_type(8))) __bf16 bf16x8;
typedef __attribute__((ext_vector_type(4))) float  f32x4;
typedef unsigned short u16;

// ws layout (bytes):
//   xb       : 1024*224*2          =   458752
//   Hb       : 50048*224*2         = 22421504
//   partials : 1024*782*4          =  3203072
//   invs     : 1024*4              =     4096
#define WS_XB   0
#define WS_HB   458752
#define WS_PART (458752 + 22421504)
#define WS_INV  (458752 + 22421504 + 3203072)

__device__ inline u16 f2bf(float f) {
  unsigned u = __float_as_uint(f);
  u += 0x7FFFu + ((u >> 16) & 1u);   // round-to-nearest-even
  return (u16)(u >> 16);
}

// ---- x -> bf16, K-padded ----------------------------------------------------
__global__ __launch_bounds__(64) void prep_x_kernel(const float* __restrict__ x,
                                                    u16* __restrict__ xb) {
  const int row = blockIdx.x;
  const int lane = threadIdx.x;
  if (lane >= 56) return;                 // 56*4 = 224 cols
  const int col = lane * 4;
  ushort4 o = make_ushort4(0, 0, 0, 0);
  if (col < DDIM) {
    const float4 v = *reinterpret_cast<const float4*>(x + (size_t)row * DDIM + col);
    o = make_ushort4(f2bf(v.x), f2bf(v.y), f2bf(v.z), f2bf(v.w));
  }
  *reinterpret_cast<ushort4*>(xb + (size_t)row * KPAD + col) = o;
}

// ---- ragged gather + segment sum -> local_H (bf16, K-padded, N-padded) ------
// segment_ids sorted: one block per concept, binary-search its [start,end).
__global__ __launch_bounds__(64) void seg_sum_kernel(const float* __restrict__ embed,
                                                     const int* __restrict__ aid,
                                                     const int* __restrict__ sid,
                                                     u16* __restrict__ Hb) {
  const int c = blockIdx.x;               // 0 .. NPAD-1 (rows >= CSEG zeroed)
  const int lane = threadIdx.x;
  if (lane >= 56) return;
  const int col = lane * 4;
  u16 o0 = 0, o1 = 0, o2 = 0, o3 = 0;
  if (c < CSEG && col < DDIM) {
    int lo = 0, hi = TTOT;
    while (lo < hi) { int m = (lo + hi) >> 1; if (sid[m] <  c) lo = m + 1; else hi = m; }
    const int s = lo;
    hi = TTOT;
    while (lo < hi) { int m = (lo + hi) >> 1; if (sid[m] <= c) lo = m + 1; else hi = m; }
    const int e = lo;
    float a0 = 0.f, a1 = 0.f, a2 = 0.f, a3 = 0.f;
    for (int t = s; t < e; ++t) {
      const float4 v = *reinterpret_cast<const float4*>(
          embed + (size_t)aid[t] * DDIM + col);
      a0 += v.x; a1 += v.y; a2 += v.z; a3 += v.w;
    }
    o0 = f2bf(a0); o1 = f2bf(a1); o2 = f2bf(a2); o3 = f2bf(a3);
  }
  *reinterpret_cast<ushort4*>(Hb + (size_t)c * KPAD + col) = make_ushort4(o0, o1, o2, o3);
}

// ---- shared GEMM tile: 4 waves, block tile 128(M) x 64(N), K=224 ------------
// A lane mapping (16x16x32 bf16): row = lane%16, k = 8*(lane/16)+e
// D mapping: col = lane&15, row = (lane>>4)*4 + reg
__device__ inline void gemm_tile(const u16* __restrict__ xb, const u16* __restrict__ Hb,
                                 int m0, int n0, int lane, f32x4 acc[2][4]) {
  const int r  = lane & 15;
  const int ko = (lane >> 4) * 8;
  const u16* xp = xb + (size_t)(m0 + r) * KPAD + ko;
  const u16* hp = Hb + (size_t)(n0 + r) * KPAD + ko;
  for (int ks = 0; ks < KPAD / 32; ++ks) {
    const int kb = ks * 32;
    const bf16x8 a0 = *reinterpret_cast<const bf16x8*>(xp + kb);
    const bf16x8 a1 = *reinterpret_cast<const bf16x8*>(xp + 16 * KPAD + kb);
#pragma unroll
    for (int ni = 0; ni < 4; ++ni) {
      const bf16x8 b = *reinterpret_cast<const bf16x8*>(hp + (size_t)ni * 16 * KPAD + kb);
      acc[0][ni] = __builtin_amdgcn_mfma_f32_16x16x32_bf16(a0, b, acc[0][ni], 0, 0, 0);
      acc[1][ni] = __builtin_amdgcn_mfma_f32_16x16x32_bf16(a1, b, acc[1][ni], 0, 0, 0);
    }
  }
}

// ---- pass 1: per-row partial sums of exp(logit) over each N-tile ------------
__global__ __launch_bounds__(256) void gemm_pass1_kernel(const u16* __restrict__ xb,
                                                         const u16* __restrict__ Hb,
                                                         float* __restrict__ partials) {
  const int ntile = blockIdx.x, mtile = blockIdx.y;
  const int lane = threadIdx.x & 63, wave = threadIdx.x >> 6;
  const int m0 = mtile * 128 + wave * 32;
  const int n0 = ntile * NTILE;
  f32x4 acc[2][4] = {};
  gemm_tile(xb, Hb, m0, n0, lane, acc);
  const int cbase = n0 + (lane & 15);
#pragma unroll
  for (int mi = 0; mi < 2; ++mi) {
#pragma unroll
    for (int rr = 0; rr < 4; ++rr) {
      float s = 0.f;
#pragma unroll
      for (int ni = 0; ni < 4; ++ni) {
        if (cbase + ni * 16 < CSEG) s += __expf(acc[mi][ni][rr]);
      }
      // reduce across the 16 lanes of each lane-group (xor < 16 stays in group)
      for (int off = 1; off < 16; off <<= 1) s += __shfl_xor(s, off, 64);
      if ((lane & 15) == 0) {
        const int row = m0 + mi * 16 + (lane >> 4) * 4 + rr;
        partials[(size_t)row * NT + ntile] = s;
      }
    }
  }
}

// ---- reduce partial sums -> 1/rowsum ----------------------------------------
__global__ __launch_bounds__(256) void reduce_kernel(const float* __restrict__ partials,
                                                     float* __restrict__ invs) {
  const int row = blockIdx.x, tid = threadIdx.x;
  float s = 0.f;
  for (int nt = tid; nt < NT; nt += 256) s += partials[(size_t)row * NT + nt];
  __shared__ float sm[256];
  sm[tid] = s;
  __syncthreads();
  for (int st = 128; st > 0; st >>= 1) {
    if (tid < st) sm[tid] += sm[tid + st];
    __syncthreads();
  }
  if (tid == 0) invs[row] = 1.0f / sm[0];
}

// ---- pass 2: recompute logits, write exp(l) * inv to d_out ------------------
__global__ __launch_bounds__(256) void gemm_pass2_kernel(const u16* __restrict__ xb,
                                                         const u16* __restrict__ Hb,
                                                         const float* __restrict__ invs,
                                                         float* __restrict__ out) {
  const int ntile = blockIdx.x, mtile = blockIdx.y;
  const int lane = threadIdx.x & 63, wave = threadIdx.x >> 6;
  const int m0 = mtile * 128 + wave * 32;
  const int n0 = ntile * NTILE;
  f32x4 acc[2][4] = {};
  gemm_tile(xb, Hb, m0, n0, lane, acc);
  const int c0 = n0 + (lane & 15);
#pragma unroll
  for (int mi = 0; mi < 2; ++mi) {
#pragma unroll
    for (int rr = 0; rr < 4; ++rr) {
      const int row = m0 + mi * 16 + (lane >> 4) * 4 + rr;
      const float inv = invs[row];
      float* orow = out + (size_t)row * CSEG;
#pragma unroll
      for (int ni = 0; ni < 4; ++ni) {
        const int col = c0 + ni * 16;
        if (col < CSEG) orow[col] = __expf(acc[mi][ni][rr]) * inv;
      }
    }
  }
}

extern "C" void kernel_launch(void* const* d_in, const int* in_sizes, int n_in,
                              void* d_out, int out_size, void* d_ws, size_t ws_size,
                              hipStream_t stream) {
  const float* x     = (const float*)d_in[0];
  const float* embed = (const float*)d_in[1];
  const int*   aid   = (const int*)d_in[2];
  const int*   sid   = (const int*)d_in[3];
  // d_in[4] = n_concepts (scalar) -- hard-coded as CSEG

  char* ws = (char*)d_ws;
  u16*   xb       = (u16*)(ws + WS_XB);
  u16*   Hb       = (u16*)(ws + WS_HB);
  float* partials = (float*)(ws + WS_PART);
  float* invs     = (float*)(ws + WS_INV);
  float* out      = (float*)d_out;

  hipLaunchKernelGGL(prep_x_kernel,   dim3(BROWS),      dim3(64),  0, stream, x, xb);
  hipLaunchKernelGGL(seg_sum_kernel,  dim3(NPAD),       dim3(64),  0, stream, embed, aid, sid, Hb);
  hipLaunchKernelGGL(gemm_pass1_kernel, dim3(NT, MTILES), dim3(256), 0, stream, xb, Hb, partials);
  hipLaunchKernelGGL(reduce_kernel,   dim3(BROWS),      dim3(256), 0, stream, partials, invs);
  hipLaunchKernelGGL(gemm_pass2_kernel, dim3(NT, MTILES), dim3(256), 0, stream, xb, Hb, invs, out);
}

// Round 2
// 325.869 us; speedup vs baseline: 1.0681x; 1.0681x over previous
//
#include <hip/hip_runtime.h>
#include <hip/hip_bf16.h>

// Problem constants (fixed by the reference)
#define DDIM   200
#define CSEG   50000
#define TTOT   1000000
#define BROWS  1024
#define KPAD   224      // 7 * 32 (K padded for mfma 16x16x32)
#define NTILE  64
#define NT     782      // ceil(50000/64)
#define NPAD   50048    // NT*64
#define MTILES 8        // 1024 / 128

typedef __attribute__((ext_vector_type(8))) __bf16 bf16x8;
typedef __attribute__((ext_vector_type(4))) float  f32x4;
typedef unsigned short u16;

// ws layout (bytes)
#define WS_XB    0
#define WS_HB    458752
#define WS_PART  (458752 + 22421504)
#define WS_INV   (458752 + 22421504 + 3203072)
#define WS_START (458752 + 22421504 + 3203072 + 4096)

__device__ inline u16 f2bf(float f) {
  unsigned u = __float_as_uint(f);
  u += 0x7FFFu + ((u >> 16) & 1u);   // round-to-nearest-even
  return (u16)(u >> 16);
}

// ---- x -> bf16, K-padded ----------------------------------------------------
__global__ __launch_bounds__(64) void prep_x_kernel(const float* __restrict__ x,
                                                    u16* __restrict__ xb) {
  const int row = blockIdx.x;
  const int lane = threadIdx.x;
  if (lane >= 56) return;                 // 56*4 = 224 cols
  const int col = lane * 4;
  ushort4 o = make_ushort4(0, 0, 0, 0);
  if (col < DDIM) {
    const float4 v = *reinterpret_cast<const float4*>(x + (size_t)row * DDIM + col);
    o = make_ushort4(f2bf(v.x), f2bf(v.y), f2bf(v.z), f2bf(v.w));
  }
  *reinterpret_cast<ushort4*>(xb + (size_t)row * KPAD + col) = o;
}

// ---- segment starts from sorted segment_ids ---------------------------------
// start[c] = first t with sid[t] >= c ; start[CSEG] = TTOT
__global__ __launch_bounds__(256) void seg_start_kernel(const int* __restrict__ sid,
                                                        int* __restrict__ start) {
  const int t = blockIdx.x * 256 + threadIdx.x;
  if (t >= TTOT) return;
  const int cur = sid[t];
  const int prev = (t == 0) ? -1 : sid[t - 1];
  for (int c = prev + 1; c <= cur; ++c) start[c] = t;
  if (t == TTOT - 1) {
    for (int c = cur + 1; c <= CSEG; ++c) start[c] = TTOT;
  }
}

// ---- ragged gather + segment sum -> local_H (bf16, K-padded, N-padded) ------
// 4 waves/block, one concept per wave; 4-way unrolled gather for MLP.
__global__ __launch_bounds__(256) void seg_sum_kernel(const float* __restrict__ embed,
                                                      const int* __restrict__ aid,
                                                      const int* __restrict__ start,
                                                      u16* __restrict__ Hb) {
  const int wave = threadIdx.x >> 6;
  const int lane = threadIdx.x & 63;
  const int c = blockIdx.x * 4 + wave;
  if (c >= NPAD || lane >= 56) return;
  const int col = lane * 4;
  const bool act = (col < DDIM);          // lanes 0..49 load; 50..55 pad zeros
  float4 a0 = {0.f, 0.f, 0.f, 0.f}, a1 = a0, a2 = a0, a3 = a0;
  if (c < CSEG && act) {
    const int s = start[c], e = start[c + 1];
    int t = s;
    for (; t + 4 <= e; t += 4) {
      const int i0 = aid[t], i1 = aid[t + 1], i2 = aid[t + 2], i3 = aid[t + 3];
      const float4 v0 = *reinterpret_cast<const float4*>(embed + (size_t)i0 * DDIM + col);
      const float4 v1 = *reinterpret_cast<const float4*>(embed + (size_t)i1 * DDIM + col);
      const float4 v2 = *reinterpret_cast<const float4*>(embed + (size_t)i2 * DDIM + col);
      const float4 v3 = *reinterpret_cast<const float4*>(embed + (size_t)i3 * DDIM + col);
      a0.x += v0.x; a0.y += v0.y; a0.z += v0.z; a0.w += v0.w;
      a1.x += v1.x; a1.y += v1.y; a1.z += v1.z; a1.w += v1.w;
      a2.x += v2.x; a2.y += v2.y; a2.z += v2.z; a2.w += v2.w;
      a3.x += v3.x; a3.y += v3.y; a3.z += v3.z; a3.w += v3.w;
    }
    for (; t < e; ++t) {
      const int i0 = aid[t];
      const float4 v0 = *reinterpret_cast<const float4*>(embed + (size_t)i0 * DDIM + col);
      a0.x += v0.x; a0.y += v0.y; a0.z += v0.z; a0.w += v0.w;
    }
    a0.x += a1.x + a2.x + a3.x;
    a0.y += a1.y + a2.y + a3.y;
    a0.z += a1.z + a2.z + a3.z;
    a0.w += a1.w + a2.w + a3.w;
  }
  const ushort4 o = make_ushort4(f2bf(a0.x), f2bf(a0.y), f2bf(a0.z), f2bf(a0.w));
  *reinterpret_cast<ushort4*>(Hb + (size_t)c * KPAD + col) =
      (c < CSEG && act) ? o : make_ushort4(0, 0, 0, 0);
}

// ---- shared GEMM tile: 4 waves, block tile 128(M) x 64(N), K=224 ------------
__device__ inline void gemm_tile(const u16* __restrict__ xb, const u16* __restrict__ Hb,
                                 int m0, int n0, int lane, f32x4 acc[2][4]) {
  const int r  = lane & 15;
  const int ko = (lane >> 4) * 8;
  const u16* xp = xb + (size_t)(m0 + r) * KPAD + ko;
  const u16* hp = Hb + (size_t)(n0 + r) * KPAD + ko;
  for (int ks = 0; ks < KPAD / 32; ++ks) {
    const int kb = ks * 32;
    const bf16x8 a0 = *reinterpret_cast<const bf16x8*>(xp + kb);
    const bf16x8 a1 = *reinterpret_cast<const bf16x8*>(xp + 16 * KPAD + kb);
#pragma unroll
    for (int ni = 0; ni < 4; ++ni) {
      const bf16x8 b = *reinterpret_cast<const bf16x8*>(hp + (size_t)ni * 16 * KPAD + kb);
      acc[0][ni] = __builtin_amdgcn_mfma_f32_16x16x32_bf16(a0, b, acc[0][ni], 0, 0, 0);
      acc[1][ni] = __builtin_amdgcn_mfma_f32_16x16x32_bf16(a1, b, acc[1][ni], 0, 0, 0);
    }
  }
}

// ---- pass 1: per-row partial sums of exp(logit) over each N-tile ------------
__global__ __launch_bounds__(256) void gemm_pass1_kernel(const u16* __restrict__ xb,
                                                         const u16* __restrict__ Hb,
                                                         float* __restrict__ partials) {
  const int ntile = blockIdx.x, mtile = blockIdx.y;
  const int lane = threadIdx.x & 63, wave = threadIdx.x >> 6;
  const int m0 = mtile * 128 + wave * 32;
  const int n0 = ntile * NTILE;
  f32x4 acc[2][4] = {};
  gemm_tile(xb, Hb, m0, n0, lane, acc);
  const int cbase = n0 + (lane & 15);
#pragma unroll
  for (int mi = 0; mi < 2; ++mi) {
#pragma unroll
    for (int rr = 0; rr < 4; ++rr) {
      float s = 0.f;
#pragma unroll
      for (int ni = 0; ni < 4; ++ni) {
        if (cbase + ni * 16 < CSEG) s += __expf(acc[mi][ni][rr]);
      }
      for (int off = 1; off < 16; off <<= 1) s += __shfl_xor(s, off, 64);
      if ((lane & 15) == 0) {
        const int row = m0 + mi * 16 + (lane >> 4) * 4 + rr;
        partials[(size_t)row * NT + ntile] = s;
      }
    }
  }
}

// ---- reduce partial sums -> 1/rowsum ----------------------------------------
__global__ __launch_bounds__(256) void reduce_kernel(const float* __restrict__ partials,
                                                     float* __restrict__ invs) {
  const int row = blockIdx.x, tid = threadIdx.x;
  float s = 0.f;
  for (int nt = tid; nt < NT; nt += 256) s += partials[(size_t)row * NT + nt];
  __shared__ float sm[256];
  sm[tid] = s;
  __syncthreads();
  for (int st = 128; st > 0; st >>= 1) {
    if (tid < st) sm[tid] += sm[tid + st];
    __syncthreads();
  }
  if (tid == 0) invs[row] = 1.0f / sm[0];
}

// ---- pass 2: recompute logits, write exp(l) * inv to d_out ------------------
__global__ __launch_bounds__(256) void gemm_pass2_kernel(const u16* __restrict__ xb,
                                                         const u16* __restrict__ Hb,
                                                         const float* __restrict__ invs,
                                                         float* __restrict__ out) {
  const int ntile = blockIdx.x, mtile = blockIdx.y;
  const int lane = threadIdx.x & 63, wave = threadIdx.x >> 6;
  const int m0 = mtile * 128 + wave * 32;
  const int n0 = ntile * NTILE;
  f32x4 acc[2][4] = {};
  gemm_tile(xb, Hb, m0, n0, lane, acc);
  const int c0 = n0 + (lane & 15);
#pragma unroll
  for (int mi = 0; mi < 2; ++mi) {
#pragma unroll
    for (int rr = 0; rr < 4; ++rr) {
      const int row = m0 + mi * 16 + (lane >> 4) * 4 + rr;
      const float inv = invs[row];
      float* orow = out + (size_t)row * CSEG;
#pragma unroll
      for (int ni = 0; ni < 4; ++ni) {
        const int col = c0 + ni * 16;
        if (col < CSEG) orow[col] = __expf(acc[mi][ni][rr]) * inv;
      }
    }
  }
}

extern "C" void kernel_launch(void* const* d_in, const int* in_sizes, int n_in,
                              void* d_out, int out_size, void* d_ws, size_t ws_size,
                              hipStream_t stream) {
  const float* x     = (const float*)d_in[0];
  const float* embed = (const float*)d_in[1];
  const int*   aid   = (const int*)d_in[2];
  const int*   sid   = (const int*)d_in[3];

  char* ws = (char*)d_ws;
  u16*   xb       = (u16*)(ws + WS_XB);
  u16*   Hb       = (u16*)(ws + WS_HB);
  float* partials = (float*)(ws + WS_PART);
  float* invs     = (float*)(ws + WS_INV);
  int*   start    = (int*)(ws + WS_START);
  float* out      = (float*)d_out;

  hipLaunchKernelGGL(prep_x_kernel,     dim3(BROWS),            dim3(64),  0, stream, x, xb);
  hipLaunchKernelGGL(seg_start_kernel,  dim3((TTOT + 255) / 256), dim3(256), 0, stream, sid, start);
  hipLaunchKernelGGL(seg_sum_kernel,    dim3(NPAD / 4),         dim3(256), 0, stream, embed, aid, start, Hb);
  hipLaunchKernelGGL(gemm_pass1_kernel, dim3(NT, MTILES),       dim3(256), 0, stream, xb, Hb, partials);
  hipLaunchKernelGGL(reduce_kernel,     dim3(BROWS),            dim3(256), 0, stream, partials, invs);
  hipLaunchKernelGGL(gemm_pass2_kernel, dim3(NT, MTILES),       dim3(256), 0, stream, xb, Hb, invs, out);
}

// Round 3
// 318.484 us; speedup vs baseline: 1.0929x; 1.0232x over previous
//
#include <hip/hip_runtime.h>
#include <hip/hip_bf16.h>

// Problem constants (fixed by the reference)
#define DDIM   200
#define CSEG   50000
#define TTOT   1000000
#define BROWS  1024
#define KPAD   224      // 7 * 32 (K padded for mfma 16x16x32)
#define NTILE  64
#define NT     782      // ceil(50000/64)
#define NPAD   50048    // NT*64
#define MTILES 8        // 1024 / 128
#define GEMM_BLOCKS (NT * MTILES)   // 6256 = 8 * 782 exactly

typedef __attribute__((ext_vector_type(8))) __bf16 bf16x8;
typedef __attribute__((ext_vector_type(4))) float  f32x4;
typedef unsigned short u16;

// ws layout (bytes)
#define WS_XB    0
#define WS_HB    458752
#define WS_PART  (458752 + 22421504)
#define WS_INV   (458752 + 22421504 + 3203072)
#define WS_START (458752 + 22421504 + 3203072 + 4096)

__device__ inline u16 f2bf(float f) {
  unsigned u = __float_as_uint(f);
  u += 0x7FFFu + ((u >> 16) & 1u);   // round-to-nearest-even
  return (u16)(u >> 16);
}

// ---- fused: segment starts (sorted sid) + x -> bf16 K-padded ----------------
__global__ __launch_bounds__(256) void fused_prep_kernel(const int* __restrict__ sid,
                                                         int* __restrict__ start,
                                                         const float* __restrict__ x,
                                                         u16* __restrict__ xb) {
  const int gtid = blockIdx.x * 256 + threadIdx.x;
  // part 1: segment boundary detection
  if (gtid < TTOT) {
    const int cur = sid[gtid];
    const int prev = (gtid == 0) ? -1 : sid[gtid - 1];
    for (int c = prev + 1; c <= cur; ++c) start[c] = gtid;
    if (gtid == TTOT - 1) {
      for (int c = cur + 1; c <= CSEG; ++c) start[c] = TTOT;
    }
  }
  // part 2: x -> bf16 (1024 rows x 56 ushort4 slots)
  if (gtid < BROWS * 56) {
    const int row = gtid / 56;
    const int col = (gtid % 56) * 4;
    ushort4 o = make_ushort4(0, 0, 0, 0);
    if (col < DDIM) {
      const float4 v = *reinterpret_cast<const float4*>(x + (size_t)row * DDIM + col);
      o = make_ushort4(f2bf(v.x), f2bf(v.y), f2bf(v.z), f2bf(v.w));
    }
    *reinterpret_cast<ushort4*>(xb + (size_t)row * KPAD + col) = o;
  }
}

// ---- ragged gather + segment sum -> local_H (bf16, K-padded, N-padded) ------
// 4 waves/block, one concept per wave; masked 8-deep gather (no scalar tail).
__global__ __launch_bounds__(256) void seg_sum_kernel(const float* __restrict__ embed,
                                                      const int* __restrict__ aid,
                                                      const int* __restrict__ start,
                                                      u16* __restrict__ Hb) {
  const int wave = threadIdx.x >> 6;
  const int lane = threadIdx.x & 63;
  const int c = blockIdx.x * 4 + wave;
  if (c >= NPAD || lane >= 56) return;
  const int col = lane * 4;
  const bool act = (col < DDIM);          // lanes 0..49 load; 50..55 pad zeros
  float4 a[8];
#pragma unroll
  for (int j = 0; j < 8; ++j) a[j] = make_float4(0.f, 0.f, 0.f, 0.f);
  if (c < CSEG && act) {
    const int s = start[c], e = start[c + 1];
    for (int t = s; t < e; t += 8) {
      int   idx[8];
      float msk[8];
#pragma unroll
      for (int j = 0; j < 8; ++j) {
        const int tt = t + j;
        const bool ok = (tt < e);
        idx[j] = aid[ok ? tt : s];
        msk[j] = ok ? 1.f : 0.f;
      }
#pragma unroll
      for (int j = 0; j < 8; ++j) {
        const float4 v = *reinterpret_cast<const float4*>(
            embed + (size_t)idx[j] * DDIM + col);
        a[j].x = fmaf(msk[j], v.x, a[j].x);
        a[j].y = fmaf(msk[j], v.y, a[j].y);
        a[j].z = fmaf(msk[j], v.z, a[j].z);
        a[j].w = fmaf(msk[j], v.w, a[j].w);
      }
    }
#pragma unroll
    for (int j = 4; j < 8; ++j) {
      a[j - 4].x += a[j].x; a[j - 4].y += a[j].y;
      a[j - 4].z += a[j].z; a[j - 4].w += a[j].w;
    }
    a[0].x += a[1].x + a[2].x + a[3].x;
    a[0].y += a[1].y + a[2].y + a[3].y;
    a[0].z += a[1].z + a[2].z + a[3].z;
    a[0].w += a[1].w + a[2].w + a[3].w;
  }
  const ushort4 o = (c < CSEG && act)
      ? make_ushort4(f2bf(a[0].x), f2bf(a[0].y), f2bf(a[0].z), f2bf(a[0].w))
      : make_ushort4(0, 0, 0, 0);
  *reinterpret_cast<ushort4*>(Hb + (size_t)c * KPAD + col) = o;
}

// ---- XCD-aware block swizzle: XCD k owns a contiguous ntile range -----------
// GEMM_BLOCKS = 6256 = 8 XCDs * 782; HW round-robins blockIdx%8 across XCDs.
__device__ inline void gemm_block_map(int orig, int* ntile, int* mtile) {
  const int f = (orig & 7) * (GEMM_BLOCKS / 8) + (orig >> 3);
  *ntile = f >> 3;          // 0..781
  *mtile = f & 7;           // 0..7  (8 m-tiles consecutive on same XCD)
}

// ---- shared GEMM tile: 4 waves, block tile 128(M) x 64(N), K=224 ------------
__device__ inline void gemm_tile(const u16* __restrict__ xb, const u16* __restrict__ Hb,
                                 int m0, int n0, int lane, f32x4 acc[2][4]) {
  const int r  = lane & 15;
  const int ko = (lane >> 4) * 8;
  const u16* xp = xb + (size_t)(m0 + r) * KPAD + ko;
  const u16* hp = Hb + (size_t)(n0 + r) * KPAD + ko;
  for (int ks = 0; ks < KPAD / 32; ++ks) {
    const int kb = ks * 32;
    const bf16x8 a0 = *reinterpret_cast<const bf16x8*>(xp + kb);
    const bf16x8 a1 = *reinterpret_cast<const bf16x8*>(xp + 16 * KPAD + kb);
#pragma unroll
    for (int ni = 0; ni < 4; ++ni) {
      const bf16x8 b = *reinterpret_cast<const bf16x8*>(hp + (size_t)ni * 16 * KPAD + kb);
      acc[0][ni] = __builtin_amdgcn_mfma_f32_16x16x32_bf16(a0, b, acc[0][ni], 0, 0, 0);
      acc[1][ni] = __builtin_amdgcn_mfma_f32_16x16x32_bf16(a1, b, acc[1][ni], 0, 0, 0);
    }
  }
}

// ---- pass 1: per-row partial sums of exp(logit) over each N-tile ------------
__global__ __launch_bounds__(256) void gemm_pass1_kernel(const u16* __restrict__ xb,
                                                         const u16* __restrict__ Hb,
                                                         float* __restrict__ partials) {
  int ntile, mtile;
  gemm_block_map(blockIdx.x, &ntile, &mtile);
  const int lane = threadIdx.x & 63, wave = threadIdx.x >> 6;
  const int m0 = mtile * 128 + wave * 32;
  const int n0 = ntile * NTILE;
  f32x4 acc[2][4] = {};
  gemm_tile(xb, Hb, m0, n0, lane, acc);
  const int cbase = n0 + (lane & 15);
#pragma unroll
  for (int mi = 0; mi < 2; ++mi) {
#pragma unroll
    for (int rr = 0; rr < 4; ++rr) {
      float s = 0.f;
#pragma unroll
      for (int ni = 0; ni < 4; ++ni) {
        if (cbase + ni * 16 < CSEG) s += __expf(acc[mi][ni][rr]);
      }
      for (int off = 1; off < 16; off <<= 1) s += __shfl_xor(s, off, 64);
      if ((lane & 15) == 0) {
        const int row = m0 + mi * 16 + (lane >> 4) * 4 + rr;
        partials[(size_t)row * NT + ntile] = s;
      }
    }
  }
}

// ---- reduce partial sums -> 1/rowsum ----------------------------------------
__global__ __launch_bounds__(256) void reduce_kernel(const float* __restrict__ partials,
                                                     float* __restrict__ invs) {
  const int row = blockIdx.x, tid = threadIdx.x;
  float s = 0.f;
  for (int nt = tid; nt < NT; nt += 256) s += partials[(size_t)row * NT + nt];
  __shared__ float sm[256];
  sm[tid] = s;
  __syncthreads();
  for (int st = 128; st > 0; st >>= 1) {
    if (tid < st) sm[tid] += sm[tid + st];
    __syncthreads();
  }
  if (tid == 0) invs[row] = 1.0f / sm[0];
}

// ---- pass 2: recompute logits, write exp(l) * inv to d_out (nontemporal) ----
__global__ __launch_bounds__(256) void gemm_pass2_kernel(const u16* __restrict__ xb,
                                                         const u16* __restrict__ Hb,
                                                         const float* __restrict__ invs,
                                                         float* __restrict__ out) {
  int ntile, mtile;
  gemm_block_map(blockIdx.x, &ntile, &mtile);
  const int lane = threadIdx.x & 63, wave = threadIdx.x >> 6;
  const int m0 = mtile * 128 + wave * 32;
  const int n0 = ntile * NTILE;
  f32x4 acc[2][4] = {};
  gemm_tile(xb, Hb, m0, n0, lane, acc);
  const int c0 = n0 + (lane & 15);
#pragma unroll
  for (int mi = 0; mi < 2; ++mi) {
#pragma unroll
    for (int rr = 0; rr < 4; ++rr) {
      const int row = m0 + mi * 16 + (lane >> 4) * 4 + rr;
      const float inv = invs[row];
      float* orow = out + (size_t)row * CSEG;
#pragma unroll
      for (int ni = 0; ni < 4; ++ni) {
        const int col = c0 + ni * 16;
        if (col < CSEG) {
          __builtin_nontemporal_store(__expf(acc[mi][ni][rr]) * inv, &orow[col]);
        }
      }
    }
  }
}

extern "C" void kernel_launch(void* const* d_in, const int* in_sizes, int n_in,
                              void* d_out, int out_size, void* d_ws, size_t ws_size,
                              hipStream_t stream) {
  const float* x     = (const float*)d_in[0];
  const float* embed = (const float*)d_in[1];
  const int*   aid   = (const int*)d_in[2];
  const int*   sid   = (const int*)d_in[3];

  char* ws = (char*)d_ws;
  u16*   xb       = (u16*)(ws + WS_XB);
  u16*   Hb       = (u16*)(ws + WS_HB);
  float* partials = (float*)(ws + WS_PART);
  float* invs     = (float*)(ws + WS_INV);
  int*   start    = (int*)(ws + WS_START);
  float* out      = (float*)d_out;

  hipLaunchKernelGGL(fused_prep_kernel, dim3((TTOT + 255) / 256), dim3(256), 0, stream,
                     sid, start, x, xb);
  hipLaunchKernelGGL(seg_sum_kernel,    dim3(NPAD / 4),    dim3(256), 0, stream,
                     embed, aid, start, Hb);
  hipLaunchKernelGGL(gemm_pass1_kernel, dim3(GEMM_BLOCKS), dim3(256), 0, stream,
                     xb, Hb, partials);
  hipLaunchKernelGGL(reduce_kernel,     dim3(BROWS),       dim3(256), 0, stream,
                     partials, invs);
  hipLaunchKernelGGL(gemm_pass2_kernel, dim3(GEMM_BLOCKS), dim3(256), 0, stream,
                     xb, Hb, invs, out);
}

// Round 5
// 273.274 us; speedup vs baseline: 1.2737x; 1.1654x over previous
//
#include <hip/hip_runtime.h>
#include <hip/hip_bf16.h>

// Problem constants (fixed by the reference)
#define DDIM   200
#define CSEG   50000
#define TTOT   1000000
#define BROWS  1024
#define KPAD   224      // 7 * 32 (K padded for mfma 16x16x32)
#define NTILE  64
#define NT     782      // ceil(50000/64)
#define NPAD   50048    // NT*64
#define MTILES 8        // 1024 / 128
#define GEMM_BLOCKS (NT * MTILES)   // 6256 = 8 * 782 exactly
#define LDSROW 232      // padded LDS row stride (bf16 units): breaks bank conflicts

typedef __attribute__((ext_vector_type(8))) __bf16 bf16x8;
typedef __attribute__((ext_vector_type(4))) float  f32x4;
typedef unsigned short u16;
typedef __attribute__((ext_vector_type(8))) unsigned short u16x8;
typedef __attribute__((ext_vector_type(4))) unsigned short u16x4;

// ws layout (bytes)
#define WS_XB    0u
#define WS_HB    458752u
#define WS_PART  (WS_HB + 22421504u)
#define WS_INV   (WS_PART + 3203072u)
#define WS_START (WS_INV + 4096u)
#define WS_EBF   (WS_START + 200704u)
#define WS_TOTAL_BF16 ((size_t)WS_EBF + 160000000u)   // + bf16 embed table

__device__ inline u16 f2bf(float f) {
  unsigned u = __float_as_uint(f);
  u += 0x7FFFu + ((u >> 16) & 1u);   // round-to-nearest-even
  return (u16)(u >> 16);
}
__device__ inline float bf2f(u16 h) {
  return __uint_as_float(((unsigned)h) << 16);
}

// ---- fused: segment starts (sorted sid) + x -> bf16 K-padded ----------------
__global__ __launch_bounds__(256) void fused_prep_kernel(const int* __restrict__ sid,
                                                         int* __restrict__ start,
                                                         const float* __restrict__ x,
                                                         u16* __restrict__ xb) {
  const int gtid = blockIdx.x * 256 + threadIdx.x;
  if (gtid < TTOT) {
    const int cur = sid[gtid];
    const int prev = (gtid == 0) ? -1 : sid[gtid - 1];
    for (int c = prev + 1; c <= cur; ++c) start[c] = gtid;
    if (gtid == TTOT - 1) {
      for (int c = cur + 1; c <= CSEG; ++c) start[c] = TTOT;
    }
  }
  if (gtid < BROWS * 56) {
    const int row = gtid / 56;
    const int col = (gtid % 56) * 4;
    ushort4 o = make_ushort4(0, 0, 0, 0);
    if (col < DDIM) {
      const float4 v = *reinterpret_cast<const float4*>(x + (size_t)row * DDIM + col);
      o = make_ushort4(f2bf(v.x), f2bf(v.y), f2bf(v.z), f2bf(v.w));
    }
    *reinterpret_cast<ushort4*>(xb + (size_t)row * KPAD + col) = o;
  }
}

// ---- embed f32 -> bf16 (table becomes L3-resident: 160 MB < 256 MB) ---------
// NT loads: don't let the dying f32 stream evict the bf16 table from L3.
__global__ __launch_bounds__(256) void conv_embed_kernel(const float* __restrict__ embed,
                                                         u16* __restrict__ ebf) {
  const long long n4 = (long long)400000 * DDIM / 4;   // 20M float4
  const long long stride = (long long)gridDim.x * 256;
  for (long long i = (long long)blockIdx.x * 256 + threadIdx.x; i < n4; i += stride) {
    const f32x4 v = __builtin_nontemporal_load(reinterpret_cast<const f32x4*>(embed) + i);
    u16x4 o;
    o.x = f2bf(v.x); o.y = f2bf(v.y); o.z = f2bf(v.z); o.w = f2bf(v.w);
    *(reinterpret_cast<u16x4*>(ebf) + i) = o;
  }
}

// ---- ragged gather (bf16 table) + segment sum -> Hb -------------------------
__global__ __launch_bounds__(256) void seg_sum_bf16_kernel(const u16* __restrict__ ebf,
                                                           const int* __restrict__ aid,
                                                           const int* __restrict__ start,
                                                           u16* __restrict__ Hb) {
  const int wave = threadIdx.x >> 6;
  const int lane = threadIdx.x & 63;
  const int c = blockIdx.x * 4 + wave;
  if (c >= NPAD || lane >= 56) return;
  const int col = lane * 4;
  const bool act = (col < DDIM);
  float4 a[8];
#pragma unroll
  for (int j = 0; j < 8; ++j) a[j] = make_float4(0.f, 0.f, 0.f, 0.f);
  if (c < CSEG && act) {
    const int s = start[c], e = start[c + 1];
    for (int t = s; t < e; t += 8) {
      int   idx[8];
      float msk[8];
#pragma unroll
      for (int j = 0; j < 8; ++j) {
        const int tt = t + j;
        const bool ok = (tt < e);
        idx[j] = aid[ok ? tt : s];
        msk[j] = ok ? 1.f : 0.f;
      }
#pragma unroll
      for (int j = 0; j < 8; ++j) {
        const ushort4 v = *reinterpret_cast<const ushort4*>(
            ebf + (size_t)idx[j] * DDIM + col);
        a[j].x = fmaf(msk[j], bf2f(v.x), a[j].x);
        a[j].y = fmaf(msk[j], bf2f(v.y), a[j].y);
        a[j].z = fmaf(msk[j], bf2f(v.z), a[j].z);
        a[j].w = fmaf(msk[j], bf2f(v.w), a[j].w);
      }
    }
#pragma unroll
    for (int j = 4; j < 8; ++j) {
      a[j - 4].x += a[j].x; a[j - 4].y += a[j].y;
      a[j - 4].z += a[j].z; a[j - 4].w += a[j].w;
    }
    a[0].x += a[1].x + a[2].x + a[3].x;
    a[0].y += a[1].y + a[2].y + a[3].y;
    a[0].z += a[1].z + a[2].z + a[3].z;
    a[0].w += a[1].w + a[2].w + a[3].w;
  }
  const ushort4 o = (c < CSEG && act)
      ? make_ushort4(f2bf(a[0].x), f2bf(a[0].y), f2bf(a[0].z), f2bf(a[0].w))
      : make_ushort4(0, 0, 0, 0);
  *reinterpret_cast<ushort4*>(Hb + (size_t)c * KPAD + col) = o;
}

// ---- fallback f32 gather (ws too small for bf16 table) ----------------------
__global__ __launch_bounds__(256) void seg_sum_kernel(const float* __restrict__ embed,
                                                      const int* __restrict__ aid,
                                                      const int* __restrict__ start,
                                                      u16* __restrict__ Hb) {
  const int wave = threadIdx.x >> 6;
  const int lane = threadIdx.x & 63;
  const int c = blockIdx.x * 4 + wave;
  if (c >= NPAD || lane >= 56) return;
  const int col = lane * 4;
  const bool act = (col < DDIM);
  float4 a[8];
#pragma unroll
  for (int j = 0; j < 8; ++j) a[j] = make_float4(0.f, 0.f, 0.f, 0.f);
  if (c < CSEG && act) {
    const int s = start[c], e = start[c + 1];
    for (int t = s; t < e; t += 8) {
      int   idx[8];
      float msk[8];
#pragma unroll
      for (int j = 0; j < 8; ++j) {
        const int tt = t + j;
        const bool ok = (tt < e);
        idx[j] = aid[ok ? tt : s];
        msk[j] = ok ? 1.f : 0.f;
      }
#pragma unroll
      for (int j = 0; j < 8; ++j) {
        const float4 v = *reinterpret_cast<const float4*>(
            embed + (size_t)idx[j] * DDIM + col);
        a[j].x = fmaf(msk[j], v.x, a[j].x);
        a[j].y = fmaf(msk[j], v.y, a[j].y);
        a[j].z = fmaf(msk[j], v.z, a[j].z);
        a[j].w = fmaf(msk[j], v.w, a[j].w);
      }
    }
#pragma unroll
    for (int j = 4; j < 8; ++j) {
      a[j - 4].x += a[j].x; a[j - 4].y += a[j].y;
      a[j - 4].z += a[j].z; a[j - 4].w += a[j].w;
    }
    a[0].x += a[1].x + a[2].x + a[3].x;
    a[0].y += a[1].y + a[2].y + a[3].y;
    a[0].z += a[1].z + a[2].z + a[3].z;
    a[0].w += a[1].w + a[2].w + a[3].w;
  }
  const ushort4 o = (c < CSEG && act)
      ? make_ushort4(f2bf(a[0].x), f2bf(a[0].y), f2bf(a[0].z), f2bf(a[0].w))
      : make_ushort4(0, 0, 0, 0);
  *reinterpret_cast<ushort4*>(Hb + (size_t)c * KPAD + col) = o;
}

// ---- XCD-aware block swizzle ------------------------------------------------
__device__ inline void gemm_block_map(int orig, int* ntile, int* mtile) {
  const int f = (orig & 7) * (GEMM_BLOCKS / 8) + (orig >> 3);
  *ntile = f >> 3;
  *mtile = f & 7;
}

// ---- GEMM tile with LDS-staged B: 4 waves, 128(M) x 64(N), K=224 ------------
// A-frags preloaded to regs (overlaps staging); B staged once per block.
__device__ inline void gemm_tile_lds(const u16* __restrict__ xb,
                                     const u16* __restrict__ Hb,
                                     u16* hlds, int m0, int n0, int tid,
                                     f32x4 acc[2][4]) {
  const int lane = tid & 63;
  const int r  = lane & 15;
  const int ko = (lane >> 4) * 8;
  const u16* xp = xb + (size_t)(m0 + r) * KPAD + ko;
  bf16x8 afrag[7][2];
#pragma unroll
  for (int ks = 0; ks < 7; ++ks) {
    afrag[ks][0] = *reinterpret_cast<const bf16x8*>(xp + ks * 32);
    afrag[ks][1] = *reinterpret_cast<const bf16x8*>(xp + 16 * KPAD + ks * 32);
  }
  // stage 64x224 bf16 B-tile: 1792 ushort8 chunks, 7 per thread
#pragma unroll
  for (int k = 0; k < 7; ++k) {
    const int i = tid + k * 256;          // 0..1791
    const int row = i / 28, c8 = i % 28;  // 28 ushort8 per row
    const u16x8 h = *reinterpret_cast<const u16x8*>(
        Hb + (size_t)(n0 + row) * KPAD + c8 * 8);
    *reinterpret_cast<u16x8*>(hlds + row * LDSROW + c8 * 8) = h;
  }
  __syncthreads();
#pragma unroll
  for (int ks = 0; ks < 7; ++ks) {
#pragma unroll
    for (int ni = 0; ni < 4; ++ni) {
      const bf16x8 b = *reinterpret_cast<const bf16x8*>(
          hlds + (r + ni * 16) * LDSROW + ko + ks * 32);
      acc[0][ni] = __builtin_amdgcn_mfma_f32_16x16x32_bf16(afrag[ks][0], b, acc[0][ni], 0, 0, 0);
      acc[1][ni] = __builtin_amdgcn_mfma_f32_16x16x32_bf16(afrag[ks][1], b, acc[1][ni], 0, 0, 0);
    }
  }
}

// ---- pass 1: per-row partial sums of exp(logit) over each N-tile ------------
__global__ __launch_bounds__(256) void gemm_pass1_kernel(const u16* __restrict__ xb,
                                                         const u16* __restrict__ Hb,
                                                         float* __restrict__ partials) {
  __shared__ u16 hlds[64 * LDSROW];
  int ntile, mtile;
  gemm_block_map(blockIdx.x, &ntile, &mtile);
  const int lane = threadIdx.x & 63, wave = threadIdx.x >> 6;
  const int m0 = mtile * 128 + wave * 32;
  const int n0 = ntile * NTILE;
  f32x4 acc[2][4] = {};
  gemm_tile_lds(xb, Hb, hlds, m0, n0, threadIdx.x, acc);
  const int cbase = n0 + (lane & 15);
#pragma unroll
  for (int mi = 0; mi < 2; ++mi) {
#pragma unroll
    for (int rr = 0; rr < 4; ++rr) {
      float s = 0.f;
#pragma unroll
      for (int ni = 0; ni < 4; ++ni) {
        if (cbase + ni * 16 < CSEG) s += __expf(acc[mi][ni][rr]);
      }
      for (int off = 1; off < 16; off <<= 1) s += __shfl_xor(s, off, 64);
      if ((lane & 15) == 0) {
        const int row = m0 + mi * 16 + (lane >> 4) * 4 + rr;
        partials[(size_t)row * NT + ntile] = s;
      }
    }
  }
}

// ---- reduce partial sums -> 1/rowsum ----------------------------------------
__global__ __launch_bounds__(256) void reduce_kernel(const float* __restrict__ partials,
                                                     float* __restrict__ invs) {
  const int row = blockIdx.x, tid = threadIdx.x;
  float s = 0.f;
  for (int nt = tid; nt < NT; nt += 256) s += partials[(size_t)row * NT + nt];
  __shared__ float sm[256];
  sm[tid] = s;
  __syncthreads();
  for (int st = 128; st > 0; st >>= 1) {
    if (tid < st) sm[tid] += sm[tid + st];
    __syncthreads();
  }
  if (tid == 0) invs[row] = 1.0f / sm[0];
}

// ---- pass 2: recompute logits, write exp(l) * inv to d_out (nontemporal) ----
__global__ __launch_bounds__(256) void gemm_pass2_kernel(const u16* __restrict__ xb,
                                                         const u16* __restrict__ Hb,
                                                         const float* __restrict__ invs,
                                                         float* __restrict__ out) {
  __shared__ u16 hlds[64 * LDSROW];
  int ntile, mtile;
  gemm_block_map(blockIdx.x, &ntile, &mtile);
  const int lane = threadIdx.x & 63, wave = threadIdx.x >> 6;
  const int m0 = mtile * 128 + wave * 32;
  const int n0 = ntile * NTILE;
  f32x4 acc[2][4] = {};
  gemm_tile_lds(xb, Hb, hlds, m0, n0, threadIdx.x, acc);
  const int c0 = n0 + (lane & 15);
#pragma unroll
  for (int mi = 0; mi < 2; ++mi) {
#pragma unroll
    for (int rr = 0; rr < 4; ++rr) {
      const int row = m0 + mi * 16 + (lane >> 4) * 4 + rr;
      const float inv = invs[row];
      float* orow = out + (size_t)row * CSEG;
#pragma unroll
      for (int ni = 0; ni < 4; ++ni) {
        const int col = c0 + ni * 16;
        if (col < CSEG) {
          __builtin_nontemporal_store(__expf(acc[mi][ni][rr]) * inv, &orow[col]);
        }
      }
    }
  }
}

extern "C" void kernel_launch(void* const* d_in, const int* in_sizes, int n_in,
                              void* d_out, int out_size, void* d_ws, size_t ws_size,
                              hipStream_t stream) {
  const float* x     = (const float*)d_in[0];
  const float* embed = (const float*)d_in[1];
  const int*   aid   = (const int*)d_in[2];
  const int*   sid   = (const int*)d_in[3];

  char* ws = (char*)d_ws;
  u16*   xb       = (u16*)(ws + WS_XB);
  u16*   Hb       = (u16*)(ws + WS_HB);
  float* partials = (float*)(ws + WS_PART);
  float* invs     = (float*)(ws + WS_INV);
  int*   start    = (int*)(ws + WS_START);
  u16*   ebf      = (u16*)(ws + WS_EBF);
  float* out      = (float*)d_out;

  const bool use_bf16 = (ws_size >= WS_TOTAL_BF16);

  hipLaunchKernelGGL(fused_prep_kernel, dim3((TTOT + 255) / 256), dim3(256), 0, stream,
                     sid, start, x, xb);
  if (use_bf16) {
    hipLaunchKernelGGL(conv_embed_kernel, dim3(2048), dim3(256), 0, stream, embed, ebf);
    hipLaunchKernelGGL(seg_sum_bf16_kernel, dim3(NPAD / 4), dim3(256), 0, stream,
                       ebf, aid, start, Hb);
  } else {
    hipLaunchKernelGGL(seg_sum_kernel, dim3(NPAD / 4), dim3(256), 0, stream,
                       embed, aid, start, Hb);
  }
  hipLaunchKernelGGL(gemm_pass1_kernel, dim3(GEMM_BLOCKS), dim3(256), 0, stream,
                     xb, Hb, partials);
  hipLaunchKernelGGL(reduce_kernel,     dim3(BROWS),       dim3(256), 0, stream,
                     partials, invs);
  hipLaunchKernelGGL(gemm_pass2_kernel, dim3(GEMM_BLOCKS), dim3(256), 0, stream,
                     xb, Hb, invs, out);
}